// Round 1
// baseline (137.880 us; speedup 1.0000x reference)
//
#include <hip/hip_runtime.h>
#include <hip/hip_bf16.h>

#define N_TOK 8192
#define DIM   512
#define FDIM  128
#define BM    16

typedef __attribute__((ext_vector_type(8))) short short8;
typedef __attribute__((ext_vector_type(4))) float floatx4;

__device__ inline short f2bf(float f) {
    union { float f; unsigned u; } v; v.f = f;
    unsigned r = (v.u + 0x7FFF + ((v.u >> 16) & 1)) >> 16;  // RNE, inputs are finite
    return (short)r;
}

// Blocks [0,128): fp32 routing, wave-per-token (16 tokens/wave), block-aggregated
// bucket append. Blocks [128,896): repack w1a/w1b/w2 into bf16 MFMA B-fragment
// order: frag id f -> 512 shorts at pw[f*512 + lane*8 + j].
__global__ __launch_bounds__(256) void k_prep(
    const float* __restrict__ x,
    const float* __restrict__ wn0, const float* __restrict__ bn0,
    const float* __restrict__ wn1, const float* __restrict__ bn1,
    const float* __restrict__ wn2, const float* __restrict__ bn2,
    const float* __restrict__ w1a, const float* __restrict__ w1b,
    const float* __restrict__ w2,
    int* __restrict__ counts, int* __restrict__ lists,
    short* __restrict__ pw1a, short* __restrict__ pw1b, short* __restrict__ pw2)
{
    const int blk = blockIdx.x;
    if (blk < 128) {
        __shared__ int leafs[64];
        const int t = threadIdx.x;
        const int wave = t >> 6, lane = t & 63;
        const int d0 = lane * 8;
        float v0[8], v1[16], v2[32];
        #pragma unroll
        for (int j = 0; j < 8; ++j)  v0[j] = wn0[d0 + j];
        #pragma unroll
        for (int j = 0; j < 16; ++j) v1[j] = wn1[d0 * 2 + j];   // v1[j*2+c] = wn1[(d0+j)*2+c]
        #pragma unroll
        for (int j = 0; j < 32; ++j) v2[j] = wn2[d0 * 4 + j];   // v2[j*4+c]
        const float b0s = bn0[0];
        const float b1s[2] = {bn1[0], bn1[1]};
        const float b2s[4] = {bn2[0], bn2[1], bn2[2], bn2[3]};
        for (int i = 0; i < 16; ++i) {
            const int tok = blk * 64 + wave * 16 + i;
            const float4* xp = (const float4*)(x + tok * DIM + d0);
            const float4 xa = xp[0], xb = xp[1];
            const float xv[8] = {xa.x, xa.y, xa.z, xa.w, xb.x, xb.y, xb.z, xb.w};
            float a0 = 0.f, a1[2] = {0.f, 0.f}, a2[4] = {0.f, 0.f, 0.f, 0.f};
            #pragma unroll
            for (int j = 0; j < 8; ++j) {
                a0    += xv[j] * v0[j];
                a1[0] += xv[j] * v1[j * 2];     a1[1] += xv[j] * v1[j * 2 + 1];
                a2[0] += xv[j] * v2[j * 4];     a2[1] += xv[j] * v2[j * 4 + 1];
                a2[2] += xv[j] * v2[j * 4 + 2]; a2[3] += xv[j] * v2[j * 4 + 3];
            }
            #pragma unroll
            for (int off = 32; off >= 1; off >>= 1) {
                a0    += __shfl_xor(a0, off, 64);
                a1[0] += __shfl_xor(a1[0], off, 64);
                a1[1] += __shfl_xor(a1[1], off, 64);
                a2[0] += __shfl_xor(a2[0], off, 64);
                a2[1] += __shfl_xor(a2[1], off, 64);
                a2[2] += __shfl_xor(a2[2], off, 64);
                a2[3] += __shfl_xor(a2[3], off, 64);
            }
            // rint(sigmoid(t))=1 iff t>0; branch bit = 1 - that. (t==0 -> rint(0.5)=0 -> bit 1.)
            int p = (a0 + b0s > 0.f) ? 0 : 1;
            const float t1 = a1[p] + b1s[p];
            p = p * 2 + ((t1 > 0.f) ? 0 : 1);
            const float t2 = a2[p] + b2s[p];
            p = p * 2 + ((t2 > 0.f) ? 0 : 1);
            if (lane == 0) leafs[wave * 16 + i] = p;
        }
        __syncthreads();
        if (t < 8) {
            const int l = t;
            int c = 0;
            for (int i = 0; i < 64; ++i) c += (leafs[i] == l);
            if (c > 0) {
                int base = atomicAdd(counts + l * 16, c);
                int j = 0;
                for (int i = 0; i < 64; ++i)
                    if (leafs[i] == l) lists[l * N_TOK + base + (j++)] = blk * 64 + i;
            }
        }
    } else {
        const int wid  = (blk - 128) * 4 + (threadIdx.x >> 6);
        const int lane = threadIdx.x & 63;
        const int q = lane >> 4, m = lane & 15;
        if (wid < 2048) {
            const float* src = (wid < 1024) ? w1a : w1b;
            short*       dst = (wid < 1024) ? pw1a : pw1b;
            const int f = wid & 1023;                       // (l*16+kb)*8+nt
            const int l = f >> 7, kb = (f >> 3) & 15, nt = f & 7;
            const float* s = src + l * 65536 + (kb * 32 + q * 8) * FDIM + nt * 16 + m;
            short8 o;
            #pragma unroll
            for (int j = 0; j < 8; ++j) o[j] = f2bf(s[j * FDIM]);
            *(short8*)(dst + f * 512 + lane * 8) = o;
        } else {
            const int f = wid - 2048;                       // (l*4+kb)*32+nt
            const int l = f >> 7, kb = (f >> 5) & 3, nt = f & 31;
            const float* s = w2 + l * 65536 + (kb * 32 + q * 8) * DIM + nt * 16 + m;
            short8 o;
            #pragma unroll
            for (int j = 0; j < 8; ++j) o[j] = f2bf(s[j * DIM]);
            *(short8*)(pw2 + f * 512 + lane * 8) = o;
        }
    }
}

// One block = 16 gathered tokens of one leaf. Phase1: h=(x@w1a+b1a)*(x@w1b+b1b)
// via 16x16x32 bf16 MFMA (A from LDS, B fragments direct from packed global).
// Phase2: y = h@w2 + b2, scatter-store fp32 rows.
__global__ __launch_bounds__(256) void k_ffn(
    const float* __restrict__ x,
    const float* __restrict__ b1a, const float* __restrict__ b1b,
    const float* __restrict__ b2,
    const short* __restrict__ pw1a, const short* __restrict__ pw1b,
    const short* __restrict__ pw2,
    const int* __restrict__ counts, const int* __restrict__ lists,
    float* __restrict__ out)
{
    const int leaf = blockIdx.y;
    const int tile = blockIdx.x;
    const int cnt  = counts[leaf * 16];
    if (tile * BM >= cnt) return;

    __shared__ int   toks[BM];
    __shared__ short xs[BM][DIM + 8];    // +8 pad: row stride 1040B -> banks shift 4/row
    __shared__ short hs[BM][FDIM + 8];

    const int t = threadIdx.x;
    if (t < BM) {
        const int idx = tile * BM + t;
        toks[t] = lists[leaf * N_TOK + ((idx < cnt) ? idx : cnt - 1)];  // clamp: dup, not stored
    }
    __syncthreads();

    {   // stage x rows -> LDS bf16; thread t: row t>>4, 32 cols
        const int row = t >> 4, c0 = (t & 15) * 32;
        const float4* src = (const float4*)(x + toks[row] * DIM + c0);
        #pragma unroll
        for (int u = 0; u < 4; ++u) {
            const float4 fa = src[u * 2], fb = src[u * 2 + 1];
            short8 o;
            o[0] = f2bf(fa.x); o[1] = f2bf(fa.y); o[2] = f2bf(fa.z); o[3] = f2bf(fa.w);
            o[4] = f2bf(fb.x); o[5] = f2bf(fb.y); o[6] = f2bf(fb.z); o[7] = f2bf(fb.w);
            *(short8*)&xs[row][c0 + u * 8] = o;
        }
    }
    __syncthreads();

    const int wave = t >> 6, lane = t & 63;
    const int qd = lane >> 4, mm = lane & 15;

    // ---- phase 1: M=16, N=128 (wave handles n-tiles 2w, 2w+1), K=512
    floatx4 accA0 = {0,0,0,0}, accA1 = {0,0,0,0}, accB0 = {0,0,0,0}, accB1 = {0,0,0,0};
    const int nt0 = wave * 2, nt1 = wave * 2 + 1;
    #pragma unroll
    for (int kb = 0; kb < 16; ++kb) {
        const short8 af  = *(const short8*)&xs[mm][kb * 32 + qd * 8];
        const short8 ba0 = *(const short8*)(pw1a + (((leaf * 16 + kb) * 8 + nt0) * 512) + lane * 8);
        const short8 ba1 = *(const short8*)(pw1a + (((leaf * 16 + kb) * 8 + nt1) * 512) + lane * 8);
        const short8 bb0 = *(const short8*)(pw1b + (((leaf * 16 + kb) * 8 + nt0) * 512) + lane * 8);
        const short8 bb1 = *(const short8*)(pw1b + (((leaf * 16 + kb) * 8 + nt1) * 512) + lane * 8);
        accA0 = __builtin_amdgcn_mfma_f32_16x16x32_bf16(af, ba0, accA0, 0, 0, 0);
        accA1 = __builtin_amdgcn_mfma_f32_16x16x32_bf16(af, ba1, accA1, 0, 0, 0);
        accB0 = __builtin_amdgcn_mfma_f32_16x16x32_bf16(af, bb0, accB0, 0, 0, 0);
        accB1 = __builtin_amdgcn_mfma_f32_16x16x32_bf16(af, bb1, accB1, 0, 0, 0);
    }
    {   // gated bias epilogue -> hs (bf16), C/D layout: col=lane&15, row=qd*4+r
        const int c0 = nt0 * 16 + mm, c1 = nt1 * 16 + mm;
        const float ba0 = b1a[leaf * FDIM + c0], ba1 = b1a[leaf * FDIM + c1];
        const float bb0 = b1b[leaf * FDIM + c0], bb1 = b1b[leaf * FDIM + c1];
        #pragma unroll
        for (int r = 0; r < 4; ++r) {
            const int row = qd * 4 + r;
            hs[row][c0] = f2bf((accA0[r] + ba0) * (accB0[r] + bb0));
            hs[row][c1] = f2bf((accA1[r] + ba1) * (accB1[r] + bb1));
        }
    }
    __syncthreads();

    // ---- phase 2: M=16, N=512 (wave handles n-tiles 8w..8w+7), K=128
    floatx4 acc[8];
    #pragma unroll
    for (int j = 0; j < 8; ++j) acc[j] = (floatx4){0, 0, 0, 0};
    #pragma unroll
    for (int kb = 0; kb < 4; ++kb) {
        const short8 af = *(const short8*)&hs[mm][kb * 32 + qd * 8];
        #pragma unroll
        for (int j = 0; j < 8; ++j) {
            const int nt = wave * 8 + j;
            const short8 bf = *(const short8*)(pw2 + (((leaf * 4 + kb) * 32 + nt) * 512) + lane * 8);
            acc[j] = __builtin_amdgcn_mfma_f32_16x16x32_bf16(af, bf, acc[j], 0, 0, 0);
        }
    }
    const int rem = cnt - tile * BM;
    #pragma unroll
    for (int j = 0; j < 8; ++j) {
        const int col = (wave * 8 + j) * 16 + mm;
        const float bias = b2[leaf * DIM + col];
        #pragma unroll
        for (int r = 0; r < 4; ++r) {
            const int row = qd * 4 + r;
            if (row < rem) out[toks[row] * DIM + col] = acc[j][r] + bias;
        }
    }
}

extern "C" void kernel_launch(void* const* d_in, const int* in_sizes, int n_in,
                              void* d_out, int out_size, void* d_ws, size_t ws_size,
                              hipStream_t stream) {
    const float* x   = (const float*)d_in[0];
    // d_in[1] = training (forward value identical either way; ignored)
    const float* wn0 = (const float*)d_in[2];
    const float* bn0 = (const float*)d_in[3];
    const float* wn1 = (const float*)d_in[4];
    const float* bn1 = (const float*)d_in[5];
    const float* wn2 = (const float*)d_in[6];
    const float* bn2 = (const float*)d_in[7];
    const float* w1a = (const float*)d_in[8];
    const float* b1a = (const float*)d_in[9];
    const float* w1b = (const float*)d_in[10];
    const float* b1b = (const float*)d_in[11];
    const float* w2  = (const float*)d_in[12];
    const float* b2  = (const float*)d_in[13];
    float* out = (float*)d_out;

    char* ws = (char*)d_ws;
    int*   counts = (int*)(ws);                               // 8 counters, stride 16 ints
    int*   lists  = (int*)(ws + 512);                         // 8 x 8192 ints
    short* pw1a   = (short*)(ws + 262656);                    // 1024 frags x 512 bf16
    short* pw1b   = (short*)(ws + 262656 + 1048576);
    short* pw2    = (short*)(ws + 262656 + 2097152);

    hipMemsetAsync(counts, 0, 512, stream);
    k_prep<<<896, 256, 0, stream>>>(x, wn0, bn0, wn1, bn1, wn2, bn2,
                                    w1a, w1b, w2, counts, lists, pw1a, pw1b, pw2);
    k_ffn<<<dim3(512, 8), 256, 0, stream>>>(x, b1a, b1b, b2, pw1a, pw1b, pw2,
                                            counts, lists, out);
}